// Round 5
// baseline (182.122 us; speedup 1.0000x reference)
//
#include <hip/hip_runtime.h>

#define CHANNELS 3
#define HW 512
#define KS 15
#define GPAD 7
#define TILE_W 32
#define TILE_H 64
#define HT (TILE_H + 2 * GPAD)   // 78 staged input rows (tile + vertical halo)
#define IN_STR 49                // odd stride: all LDS phases <=2-way aliasing (free)
#define WCOLS 12                 // 12 float4 = 48 staged cols [gx0-8, gx0+40)
                                 // 48 = 1.5x banks -> staging writes max 2-way (r4's 80-wide was 3-way)
#define NSTAGE (HT * WCOLS)      // 936 float4 stage items
#define NH (HT * (TILE_W / 16))  // 156 h-pass items (row, 16-col chunk)
#define WIN (16 + KS - 1)        // 30-tap window per 16-output chunk

// LDS = 78*49*4 = 15288 B -> 8 blocks/CU (32 waves, full occupancy).
// launch_bounds(256,8): VGPR cap 64; hot-phase liveness ~40, no spill.
__global__ __launch_bounds__(256, 8)
void gauss_blur_kernel(const float* __restrict__ x,
                       const float* __restrict__ sigma,
                       float* __restrict__ out) {
    // Single LDS buffer, reused in place:
    //   phase 0: input rows [gy0, gy0+78) x cols [gx0-8, gx0+40)   (78 x 48)
    //   phase 2: horizontal-pass result (mid) overwrites cols [0,32) (78 x 32)
    __shared__ float in_s[HT * IN_STR];

    const int tid   = threadIdx.x;   // 0..255
    const int tileX = blockIdx.x;    // 0..15
    const int tileY = blockIdx.y;    // 0..7
    const int bc    = blockIdx.z;    // 0..B*C-1
    const int b     = bc / CHANNELS;

    const size_t plane = (size_t)HW * HW;
    const float* xp = x + (size_t)bc * plane;
    float* op       = out + (size_t)bc * plane;
    const int gx0 = tileX * TILE_W;         // first output col of tile
    const int gy0 = tileY * TILE_H - GPAD;  // first staged row (global)
    const int ax0 = gx0 - 8;                // 16B-aligned staged-window start col
    // block-uniform: staged window fully in-image -> zero per-element bounds code
    const bool interior = (tileX >= 1) && (tileX <= (HW / TILE_W) - 2) &&
                          (tileY >= 1) && (tileY <= (HW / TILE_H) - 2);

    // ---- phase 0a: ISSUE the staging burst — 4 independent float4 loads per
    // thread, no consumer in between (MLP engine; r4's win). ----
    float4 v[4];
    #pragma unroll
    for (int s = 0; s < 4; ++s) v[s] = make_float4(0.f, 0.f, 0.f, 0.f);
    if (interior) {
        #pragma unroll
        for (int s = 0; s < 4; ++s) {
            const int i = tid + 256 * s;
            if (i < NSTAGE) {
                const int r = i / WCOLS;
                const int q = i - r * WCOLS;
                v[s] = *(const float4*)(xp + (size_t)(gy0 + r) * HW + (ax0 + 4 * q));
            }
        }
    } else {
        #pragma unroll
        for (int s = 0; s < 4; ++s) {
            const int i = tid + 256 * s;
            if (i < NSTAGE) {
                const int r  = i / WCOLS;
                const int q  = i - r * WCOLS;
                const int gy = gy0 + r;
                const int gc = ax0 + 4 * q;
                if ((unsigned)gy < (unsigned)HW) {
                    const float* rowp = xp + (size_t)gy * HW;
                    if (gc >= 0 && gc + 4 <= HW) {
                        v[s] = *(const float4*)(rowp + gc);
                    } else {
                        if ((unsigned)(gc + 0) < (unsigned)HW) v[s].x = rowp[gc + 0];
                        if ((unsigned)(gc + 1) < (unsigned)HW) v[s].y = rowp[gc + 1];
                        if ((unsigned)(gc + 2) < (unsigned)HW) v[s].z = rowp[gc + 2];
                        if ((unsigned)(gc + 3) < (unsigned)HW) v[s].w = rowp[gc + 3];
                    }
                }
            }
        }
    }

    // ---- weights: computed while staging loads are in flight (independent of
    // v[]); wave-uniform -> pin to SGPRs via readfirstlane. ----
    float w[KS];
    {
        const float s = sigma[b];
        const float inv_denom = 1.0f / (2.0f * s * s + 1e-8f);
        float g[KS];
        float sum = 0.0f;
        #pragma unroll
        for (int i = 0; i < KS; ++i) {
            const float d = (float)(i - GPAD);
            g[i] = __expf(-d * d * inv_denom);
            sum += g[i];
        }
        const float inv = 1.0f / sum;
        #pragma unroll
        for (int i = 0; i < KS; ++i)
            w[i] = __int_as_float(__builtin_amdgcn_readfirstlane(__float_as_int(g[i] * inv)));
    }

    // ---- phase 0b: drain loads into LDS (48-wide rows: writes <=2-way = free) ----
    #pragma unroll
    for (int s = 0; s < 4; ++s) {
        const int i = tid + 256 * s;
        if (i < NSTAGE) {
            const int r = i / WCOLS;
            const int q = i - r * WCOLS;
            float* d = &in_s[r * IN_STR + 4 * q];
            d[0] = v[s].x; d[1] = v[s].y; d[2] = v[s].z; d[3] = v[s].w;
        }
    }
    __syncthreads();

    // ---- phase 1: horizontal pass, LDS -> registers (accumulate on load).
    // Item tid -> (row r = tid>>1, 16-col chunk ch = tid&1); 156 items, 1 round.
    // Output local col oc = 16ch+o reads staged cols [oc+1, oc+30). Tap order
    // identical to baseline (ascending j, w[j-o]). Banks: 17r bijective mod 32,
    // ch adds 16 -> exactly 2-way = free. ----
    float acc[16];
    #pragma unroll
    for (int o = 0; o < 16; ++o) acc[o] = 0.0f;
    const bool hwork = (tid < NH);
    if (hwork) {
        const int r  = tid >> 1;
        const int ch = tid & 1;
        const float* src = &in_s[r * IN_STR + 16 * ch + 1];
        #pragma unroll
        for (int j = 0; j < WIN; ++j) {
            const float vv = src[j];
            const int lo = (j - (KS - 1)) > 0 ? (j - (KS - 1)) : 0;
            const int hi = (j < 15) ? j : 15;
            #pragma unroll
            for (int o = lo; o <= hi; ++o)
                acc[o] = fmaf(w[j - o], vv, acc[o]);
        }
    }
    __syncthreads();   // all LDS reads done before in-place overwrite

    // ---- phase 2: write mid back into the same LDS buffer (cols 0..31) ----
    if (hwork) {
        const int r  = tid >> 1;
        const int ch = tid & 1;
        float* dst = &in_s[r * IN_STR + 16 * ch];
        #pragma unroll
        for (int o = 0; o < 16; ++o) dst[o] = acc[o];
    }
    __syncthreads();

    // ---- phase 3: vertical pass from LDS, accumulate on load; coalesced
    // stores. c = tid&31, r0 = (tid>>5)*8 -> 8 row-groups x 32 cols = 256. ----
    {
        const int c  = tid & (TILE_W - 1);
        const int r0 = (tid >> 5) * 8;
        float vacc[8];
        #pragma unroll
        for (int o = 0; o < 8; ++o) vacc[o] = 0.0f;
        #pragma unroll
        for (int j = 0; j < 8 + KS - 1; ++j) {     // 22 taps for 8 outputs
            const float vv = in_s[(r0 + j) * IN_STR + c];
            const int lo = (j - (KS - 1)) > 0 ? (j - (KS - 1)) : 0;
            const int hi = (j < 8) ? j : 7;
            #pragma unroll
            for (int o = lo; o <= hi; ++o)
                vacc[o] = fmaf(w[j - o], vv, vacc[o]);
        }
        float* colp = op + (size_t)(tileY * TILE_H + r0) * HW + gx0 + c;
        #pragma unroll
        for (int o = 0; o < 8; ++o)
            colp[(size_t)o * HW] = vacc[o];
    }
}

extern "C" void kernel_launch(void* const* d_in, const int* in_sizes, int n_in,
                              void* d_out, int out_size, void* d_ws, size_t ws_size,
                              hipStream_t stream) {
    const float* x     = (const float*)d_in[0];
    const float* sigma = (const float*)d_in[1];
    float* out         = (float*)d_out;
    const int B = in_sizes[1];  // 32
    dim3 grid(HW / TILE_W, HW / TILE_H, B * CHANNELS);
    gauss_blur_kernel<<<grid, dim3(256, 1, 1), 0, stream>>>(x, sigma, out);
}